// Round 6
// baseline (213.735 us; speedup 1.0000x reference)
//
#include <hip/hip_runtime.h>
#include <hip/hip_bf16.h>

#define B_  2
#define T_  2048
#define NH_ 16
#define HS_ 64
#define C_  1024
#define SCL_ 128              // EMA chunk length
#define SCN_ (T_ / SCL_)      // 16 chunks
#define NT_  (T_ / 64)        // 32 key/query tiles
#define TEL_ 4096             // elements per 64x64 tile

typedef __attribute__((ext_vector_type(8))) short bf16x8;
typedef __attribute__((ext_vector_type(4))) float f32x4;

__device__ inline int pack_bf16(float a, float b) {
  union { __hip_bfloat16 h; unsigned short u; } ua, ub;
  ua.h = __float2bfloat16(a);
  ub.h = __float2bfloat16(b);
  return (int)(((unsigned)ub.u << 16) | (unsigned)ua.u);
}

// async global->LDS 16B: global ptr is PER-LANE; LDS dest must equal
// wave-uniform base + lane*16. Callers pass per-lane g AND l = base+lane*16.
__device__ inline void gl_lds16(const __hip_bfloat16* g, __hip_bfloat16* l) {
  __builtin_amdgcn_global_load_lds(
      (const __attribute__((address_space(1))) unsigned int*)g,
      (__attribute__((address_space(3))) unsigned int*)l, 16, 0, 0);
}

// ---------------------------------------------------------------------------
// prep1: fused {fp32->bf16 x conversion} + {3x weight transpose to bf16}.
// blocks [0,2048): cvt (8 elems/thread). blocks [2048,2816): cvtT (z = id>>8).
// ---------------------------------------------------------------------------
__global__ __launch_bounds__(256) void prep1_kernel(const float* __restrict__ x,
                                                    const float* __restrict__ W_la,
                                                    const float* __restrict__ W_v,
                                                    const float* __restrict__ W_proj,
                                                    __hip_bfloat16* __restrict__ x16,
                                                    __hip_bfloat16* __restrict__ Wcat,
                                                    __hip_bfloat16* __restrict__ WprojT) {
  __shared__ __hip_bfloat16 tile[64][66];
  const int bid = (int)blockIdx.x;
  if (bid < 2048) {
    const int i = (bid * 256 + (int)threadIdx.x) * 8;
    const float4 a = *reinterpret_cast<const float4*>(x + i);
    const float4 b = *reinterpret_cast<const float4*>(x + i + 4);
    union { int s[4]; int4 v; } u;
    u.s[0] = pack_bf16(a.x, a.y);
    u.s[1] = pack_bf16(a.z, a.w);
    u.s[2] = pack_bf16(b.x, b.y);
    u.s[3] = pack_bf16(b.z, b.w);
    *reinterpret_cast<int4*>(x16 + i) = u.v;
    return;
  }
  const int id = bid - 2048;        // 0..767
  const int z = id >> 8;            // 0..2
  const int rem = id & 255;
  const int bx = rem & 15, by = rem >> 4;
  const float* W = (z == 0) ? W_la : (z == 1) ? W_v : W_proj;
  __hip_bfloat16* WT = (z == 2) ? WprojT : Wcat + (size_t)z * C_ * C_;
  const int w = threadIdx.x >> 6, l = threadIdx.x & 63;
  const int n0 = bx * 64, k0 = by * 64;
#pragma unroll
  for (int r = 0; r < 16; ++r) {
    const int k = k0 + w * 16 + r;
    tile[w * 16 + r][l] = __float2bfloat16(W[(size_t)k * C_ + n0 + l]);
  }
  __syncthreads();
#pragma unroll
  for (int r = 0; r < 16; ++r) {
    const int nn = w * 16 + r;
    WT[(size_t)(n0 + nn) * C_ + k0 + l] = tile[l][nn];
  }
}

// ---------------------------------------------------------------------------
// Combined input GEMM: [xl | xv] = x16(4096x1024) @ Wcat(2048x1024)^T.
// 2-phase double-buffered pipeline, counted vmcnt, raw s_barrier.
// ---------------------------------------------------------------------------
__global__ __launch_bounds__(256) void gemm_in_kernel(const __hip_bfloat16* __restrict__ A,
                                                      const __hip_bfloat16* __restrict__ BT,
                                                      float* __restrict__ C0,
                                                      float* __restrict__ C1) {
  __shared__ __hip_bfloat16 As[2 * 128 * 32];
  __shared__ __hip_bfloat16 Bs[2 * 128 * 32];
  const int tid = threadIdx.x;
  const int m0 = blockIdx.y * 128, n0 = blockIdx.x * 128;
  const int w = tid >> 6, l = tid & 63;
  const int n = l & 15, kg = l >> 4;
  const int m0w = (w & 1) * 64, n0w = (w >> 1) * 64;

  const int r0 = tid >> 2, o0 = (tid & 3) * 8;
  const __hip_bfloat16* ag0 = A + (size_t)(m0 + r0) * C_ + o0;
  const __hip_bfloat16* ag1 = A + (size_t)(m0 + 64 + r0) * C_ + o0;
  const __hip_bfloat16* bg0 = BT + (size_t)(n0 + r0) * C_ + o0;
  const __hip_bfloat16* bg1 = BT + (size_t)(n0 + 64 + r0) * C_ + o0;

  f32x4 acc[4][4];
#pragma unroll
  for (int i = 0; i < 4; ++i)
#pragma unroll
    for (int j = 0; j < 4; ++j) acc[i][j] = f32x4{0.f, 0.f, 0.f, 0.f};

  auto stage = [&](int kk, int buf) {
    __hip_bfloat16* a = As + buf * 4096;
    __hip_bfloat16* b = Bs + buf * 4096;
    gl_lds16(ag0 + kk, a + tid * 8);
    gl_lds16(ag1 + kk, a + 2048 + tid * 8);
    gl_lds16(bg0 + kk, b + tid * 8);
    gl_lds16(bg1 + kk, b + 2048 + tid * 8);
  };

  stage(0, 0);
  int cur = 0;
  for (int k0 = 0; k0 < C_; k0 += 32) {
    asm volatile("" ::: "memory");
    __builtin_amdgcn_s_barrier();   // buf[cur^1] readers (iter-1) done
    asm volatile("" ::: "memory");
    if (k0 + 32 < C_) {
      stage(k0 + 32, cur ^ 1);
      asm volatile("s_waitcnt vmcnt(4)" ::: "memory");  // older 4 (this tile) landed
    } else {
      asm volatile("s_waitcnt vmcnt(0)" ::: "memory");
    }
    __builtin_amdgcn_s_barrier();   // all waves' tile-k0 DMAs landed
    asm volatile("" ::: "memory");

    const __hip_bfloat16* Ab = As + cur * 4096;
    const __hip_bfloat16* Bb = Bs + cur * 4096;
    bf16x8 af[4], bf[4];
#pragma unroll
    for (int ms = 0; ms < 4; ++ms)
      af[ms] = *reinterpret_cast<const bf16x8*>(Ab + (m0w + ms * 16 + n) * 32 + kg * 8);
#pragma unroll
    for (int ns = 0; ns < 4; ++ns)
      bf[ns] = *reinterpret_cast<const bf16x8*>(Bb + (n0w + ns * 16 + n) * 32 + kg * 8);
#pragma unroll
    for (int ms = 0; ms < 4; ++ms)
#pragma unroll
      for (int ns = 0; ns < 4; ++ns)
        acc[ms][ns] = __builtin_amdgcn_mfma_f32_16x16x32_bf16(af[ms], bf[ns], acc[ms][ns], 0, 0, 0);
    cur ^= 1;
  }

  float* Cb = (n0 < C_) ? C0 : C1;
  const int nc = (n0 < C_) ? n0 : n0 - C_;
#pragma unroll
  for (int ms = 0; ms < 4; ++ms) {
#pragma unroll
    for (int r = 0; r < 4; ++r) {
      const int row = m0 + m0w + ms * 16 + kg * 4 + r;
      float* cp = Cb + (size_t)row * C_ + nc + n0w + n;
#pragma unroll
      for (int ns = 0; ns < 4; ++ns) cp[ns * 16] = acc[ms][ns][r];
    }
  }
}

// ---------------------------------------------------------------------------
// Projection GEMM: out = y16(4096x1024) @ WprojT(1024x1024)^T, fp32 out.
// ---------------------------------------------------------------------------
__global__ __launch_bounds__(256) void gemm_proj_kernel(const __hip_bfloat16* __restrict__ A,
                                                        const __hip_bfloat16* __restrict__ BT,
                                                        float* __restrict__ Cout) {
  __shared__ __hip_bfloat16 As[2 * 64 * 32];
  __shared__ __hip_bfloat16 Bs[2 * 128 * 32];
  const int tid = threadIdx.x;
  const int m0 = blockIdx.y * 64, n0 = blockIdx.x * 128;
  const int w = tid >> 6, l = tid & 63;
  const int n = l & 15, kg = l >> 4;

  const int r0 = tid >> 2, o0 = (tid & 3) * 8;
  const __hip_bfloat16* ag = A + (size_t)(m0 + r0) * C_ + o0;
  const __hip_bfloat16* bg0 = BT + (size_t)(n0 + r0) * C_ + o0;
  const __hip_bfloat16* bg1 = BT + (size_t)(n0 + 64 + r0) * C_ + o0;

  f32x4 acc[4][2];
#pragma unroll
  for (int i = 0; i < 4; ++i)
#pragma unroll
    for (int j = 0; j < 2; ++j) acc[i][j] = f32x4{0.f, 0.f, 0.f, 0.f};

  auto stage = [&](int kk, int buf) {
    __hip_bfloat16* a = As + buf * 2048;
    __hip_bfloat16* b = Bs + buf * 4096;
    gl_lds16(ag + kk, a + tid * 8);
    gl_lds16(bg0 + kk, b + tid * 8);
    gl_lds16(bg1 + kk, b + 2048 + tid * 8);
  };

  stage(0, 0);
  int cur = 0;
  for (int k0 = 0; k0 < C_; k0 += 32) {
    asm volatile("" ::: "memory");
    __builtin_amdgcn_s_barrier();
    asm volatile("" ::: "memory");
    if (k0 + 32 < C_) {
      stage(k0 + 32, cur ^ 1);
      asm volatile("s_waitcnt vmcnt(3)" ::: "memory");
    } else {
      asm volatile("s_waitcnt vmcnt(0)" ::: "memory");
    }
    __builtin_amdgcn_s_barrier();
    asm volatile("" ::: "memory");

    const __hip_bfloat16* Ab = As + cur * 2048;
    const __hip_bfloat16* Bb = Bs + cur * 4096;
    bf16x8 af[4], bf[2];
#pragma unroll
    for (int ms = 0; ms < 4; ++ms)
      af[ms] = *reinterpret_cast<const bf16x8*>(Ab + (ms * 16 + n) * 32 + kg * 8);
#pragma unroll
    for (int ns = 0; ns < 2; ++ns)
      bf[ns] = *reinterpret_cast<const bf16x8*>(Bb + (w * 32 + ns * 16 + n) * 32 + kg * 8);
#pragma unroll
    for (int ms = 0; ms < 4; ++ms)
#pragma unroll
      for (int ns = 0; ns < 2; ++ns)
        acc[ms][ns] = __builtin_amdgcn_mfma_f32_16x16x32_bf16(af[ms], bf[ns], acc[ms][ns], 0, 0, 0);
    cur ^= 1;
  }

#pragma unroll
  for (int ms = 0; ms < 4; ++ms) {
#pragma unroll
    for (int r = 0; r < 4; ++r) {
      const int row = m0 + ms * 16 + kg * 4 + r;
      float* cp = Cout + (size_t)row * C_ + n0 + w * 32 + n;
#pragma unroll
      for (int ns = 0; ns < 2; ++ns) cp[ns * 16] = acc[ms][ns][r];
    }
  }
}

// ---------------------------------------------------------------------------
// prep2: fused {vprep} (blocks [0,1024)) + {EMA pass 1} (blocks [1024,1536)).
// ---------------------------------------------------------------------------
__global__ __launch_bounds__(256) void prep2_kernel(const float* __restrict__ xv,
                                                    const float* __restrict__ xl,
                                                    __hip_bfloat16* __restrict__ vt,
                                                    float* __restrict__ loc,
                                                    float* __restrict__ carr,
                                                    const float* __restrict__ value_beta,
                                                    const float* __restrict__ v_coef,
                                                    const float* __restrict__ la_coef) {
  __shared__ float4 smem4[2048];  // 32 KB, shared by both paths
  const int bid = (int)blockIdx.x;
  if (bid < 1024) {
    // ---- vprep ----
    __hip_bfloat16 (*tile)[66] = reinterpret_cast<__hip_bfloat16(*)[66]>(smem4);
    const int tc = bid % NT_;
    const int bh = bid / NT_;
    const int h = bh % NH_, b = bh / NH_;
    const int t0 = tc * 64;
    const int w = threadIdx.x >> 6, l = threadIdx.x & 63;

    const float c = v_coef[h];
    const float vb = expf(value_beta[h] * 10.0f);

    for (int r = 0; r < 16; ++r) {
      const int tl = w * 16 + r;
      const int t = t0 + tl;
      const float* base = xv + ((size_t)b * T_ + t) * C_ + h * HS_ + l;
      const float cu = base[0];
      const float nxt = (t + 1 < T_) ? base[C_] : 0.0f;
      float val = nxt * (1.0f - c) + cu * c;
      float ssum = val * val;
#pragma unroll
      for (int m = 32; m; m >>= 1) ssum += __shfl_xor(ssum, m);
      tile[tl][l] = __float2bfloat16(val * (vb / sqrtf(ssum)));
    }
    __syncthreads();
    __hip_bfloat16* vtb = vt + (size_t)(bh * NT_ + tc) * TEL_;
    const int kk = l >> 3, j = l & 7;  // l = key
    for (int rr = 0; rr < 16; ++rr) {
      const int hs = w * 16 + rr;
      vtb[(kk * 64 + hs) * 8 + j] = tile[l][hs];
    }
    return;
  }
  // ---- EMA pass 1 ----
  {
    float* buf = reinterpret_cast<float*>(smem4);
    const int idx = bid - 1024;
    const int c = idx % SCN_;
    const int bh = idx / SCN_;
    const int b = bh / NH_, h = bh % NH_;
    const int tid = threadIdx.x;
    const int t0 = c * SCL_;

    const float alpha = la_coef[h];
    const float onema = 1.0f - alpha;
    const float4* src4 = reinterpret_cast<const float4*>(xl + (size_t)b * T_ * C_ + h * HS_);

    float4* buf4 = reinterpret_cast<float4*>(buf);
#pragma unroll
    for (int i = 0; i < (SCL_ * HS_ / 4) / 256; ++i) {  // 8 iters
      const int ix = tid + i * 256;
      const int tt = ix >> 4, d4 = ix & 15;
      buf4[tt * 16 + d4] = src4[(size_t)(t0 + tt) * (C_ / 4) + d4];
    }
    __syncthreads();
    if (tid < 64) {
      const int d = tid;
      float c2 = 0.0f;
#pragma unroll 8
      for (int tt = 0; tt < SCL_; ++tt) {
        c2 = alpha * c2 + onema * buf[tt * HS_ + d];
        buf[tt * HS_ + d] = c2;
      }
      carr[(size_t)(bh * SCN_ + c) * HS_ + d] = c2;  // chunk-final
    }
    __syncthreads();
    float4* dst4 = reinterpret_cast<float4*>(loc + ((size_t)bh * T_ + t0) * HS_);
#pragma unroll
    for (int i = 0; i < (SCL_ * HS_ / 4) / 256; ++i) dst4[tid + i * 256] = buf4[tid + i * 256];
  }
}

// ---------------------------------------------------------------------------
// EMA pass 2 (fused carry): combine chunk-finals (Horner), row-normalize,
// kb-scale, emit bf16 k in TILE-SLOT layout (BH, NT, g=hs>>3, key, 8).
// ---------------------------------------------------------------------------
__global__ __launch_bounds__(256) void ema_fix_norm_kernel(const float* __restrict__ loc,
                                                           const float* __restrict__ carr,
                                                           __hip_bfloat16* __restrict__ kb16,
                                                           const float* __restrict__ la_coef,
                                                           const float* __restrict__ kernel_beta) {
  const int c = blockIdx.x % SCN_;
  const int bh = blockIdx.x / SCN_;
  const int h = bh % NH_;
  const int w = threadIdx.x >> 6, l = threadIdx.x & 63;

  const float alpha = la_coef[h];
  const float aL = __powf(alpha, (float)SCL_);
  const float kbs = expf(fminf(kernel_beta[h] * 10.0f, 5.0f));

  float A = 0.0f;
  for (int cc = 0; cc < c; ++cc) A = aL * A + carr[(size_t)(bh * SCN_ + cc) * HS_ + l];

  const float* lp = loc + ((size_t)bh * T_ + c * SCL_ + w * 32) * HS_ + l;
  __hip_bfloat16* kt = kb16 + (size_t)bh * NT_ * TEL_;
  const int g = l >> 3, j = l & 7;

  float s = __powf(alpha, (float)(w * 32 + 1));
  for (int rr = 0; rr < 32; ++rr) {
    const int t = c * SCL_ + w * 32 + rr;
    float val = lp[rr * HS_] + s * A;
    float ss = val * val;
#pragma unroll
    for (int m = 32; m; m >>= 1) ss += __shfl_xor(ss, m);
    const int tile = t >> 6, key = t & 63;
    kt[(size_t)tile * TEL_ + (g * 64 + key) * 8 + j] = __float2bfloat16(val * (kbs / sqrtf(ss)));
    s *= alpha;
  }
}

// ---------------------------------------------------------------------------
// MFMA flash attention, 128-QUERY BLOCKS (q-tile pair) + V-DIRECT + paired
// K-tiles. Each wave owns 32 queries (two 16-q groups qg, offset 64): every
// K fragment read from LDS and every V fragment from global now feeds TWO
// MFMAs (was one) -> LDS-pipe cycles per unit work drop ~33% (the measured
// floor: MfmaUtil 15% @ 0 conflicts). P stays wave-private (no new barriers).
// Causality: tiles < 2u full; tile 2u diag(qg0)/full(qg1); tile 2u+1
// skip(qg0)/diag(qg1). Grid 512 = 32 bh x 16 pairs; balanced u-map keeps
// per-CU tile sum = 34. LDS: Ks 2buf x 2tiles 32K + Ps 16K = 48K.
// ---------------------------------------------------------------------------
__global__ __launch_bounds__(256, 2) void attn_mfma_kernel(
    const __hip_bfloat16* __restrict__ kb,   // (BH, NT, g, key, 8) slot tiles
    const __hip_bfloat16* __restrict__ vt,   // (BH, NT, kk, hs, 8) slot tiles
    __hip_bfloat16* __restrict__ y) {        // (B, T, C) bf16
  __shared__ __hip_bfloat16 Ks[2][2 * TEL_]; // 32 KB: [buf][tileA|tileB]
  __shared__ __hip_bfloat16 Ps[4][2][16 * 64];  // 16 KB: [wave][qg], XOR-swz

  const int id = (int)blockIdx.x;
  const int xcd = id & 7;
  const int s = id >> 3;                 // 0..63
  const int bh = xcd + 8 * (s & 3);      // 32 bh, grouped 4 per XCD
  const int v = s >> 2;                  // 0..15
  const int u = (v < 8) ? v : (23 - v);  // balanced: CU pair (v,v+8) sums 34
  const int b = bh / NH_, h = bh % NH_;
  const int q0 = u * 128;
  const int w = threadIdx.x >> 6;
  const int l = threadIdx.x & 63;
  const int n = l & 15;
  const int kg = l >> 4;
  const int qq = w * 16 + n;             // q index within its 64-q tile
  const int lo = l * 8;
  const int tb = bh * NT_;
  const int so = w * 1024 + lo;

  // Q B-fragments for both q-halves (tiles 2u, 2u+1 of kb)
  bf16x8 qf[2][2];
#pragma unroll
  for (int qg = 0; qg < 2; ++qg) {
    const __hip_bfloat16* qtile = kb + (size_t)(tb + 2 * u + qg) * TEL_;
    qf[qg][0] = *reinterpret_cast<const bf16x8*>(qtile + (kg * 64 + qq) * 8);
    qf[qg][1] = *reinterpret_cast<const bf16x8*>(qtile + ((kg + 4) * 64 + qq) * 8);
  }
  const __hip_bfloat16* vbase = vt + (size_t)tb * TEL_ + (kg * 64 + n) * 8;

  f32x4 accO[2][4];
#pragma unroll
  for (int qg = 0; qg < 2; ++qg)
#pragma unroll
    for (int i = 0; i < 4; ++i) accO[qg][i] = f32x4{0.f, 0.f, 0.f, 0.f};
  float l_acc[2] = {0.0f, 0.0f};

  int* Pwi[2] = {reinterpret_cast<int*>(&Ps[w][0][0]),
                 reinterpret_cast<int*>(&Ps[w][1][0])};

  auto stage2 = [&](int j0, int buf) {   // 4 DMAs: K tiles j0, j0+1
    const size_t tg = (size_t)(tb + j0) * TEL_;
    __hip_bfloat16* Kb = &Ks[buf][0];
    gl_lds16(kb + tg + so, Kb + so);
    gl_lds16(kb + tg + so + 512, Kb + so + 512);
    gl_lds16(kb + tg + TEL_ + so, Kb + TEL_ + so);
    gl_lds16(kb + tg + TEL_ + so + 512, Kb + TEL_ + so + 512);
  };
  auto loadV = [&](int jt, bf16x8 (&vf)[2][4]) {
    const __hip_bfloat16* vp = vbase + (size_t)jt * TEL_;
#pragma unroll
    for (int ks = 0; ks < 2; ++ks)
#pragma unroll
      for (int mo = 0; mo < 4; ++mo)
        vf[ks][mo] = *reinterpret_cast<const bf16x8*>(vp + ks * 2048 + mo * 128);
  };
  // S for BOTH q-groups: each K fragment read once, used twice.
  auto computeS2 = [&](const __hip_bfloat16* Kc, f32x4 (&aS)[2][4]) {
    __builtin_amdgcn_s_setprio(1);
#pragma unroll
    for (int ms = 0; ms < 4; ++ms) {
      bf16x8 a0 = *reinterpret_cast<const bf16x8*>(Kc + (kg * 64 + ms * 16 + n) * 8);
      bf16x8 a1 = *reinterpret_cast<const bf16x8*>(Kc + ((kg + 4) * 64 + ms * 16 + n) * 8);
#pragma unroll
      for (int qg = 0; qg < 2; ++qg) {
        f32x4 z{0.f, 0.f, 0.f, 0.f};
        z = __builtin_amdgcn_mfma_f32_16x16x32_bf16(a0, qf[qg][0], z, 0, 0, 0);
        aS[qg][ms] = __builtin_amdgcn_mfma_f32_16x16x32_bf16(a1, qf[qg][1], z, 0, 0, 0);
      }
    }
    __builtin_amdgcn_s_setprio(0);
  };
  // softmax for one q-group; dm: 0 = full, 1 = diagonal mask vs qq
  auto softmaxStore = [&](const f32x4 (&aS)[4], int qg, int dm) {
    if (!dm) {
#pragma unroll
      for (int ms = 0; ms < 4; ++ms) {
        const float p0 = __expf(aS[ms][0]), p1 = __expf(aS[ms][1]);
        const float p2 = __expf(aS[ms][2]), p3 = __expf(aS[ms][3]);
        l_acc[qg] += p0 + p1 + p2 + p3;
        const int po = n * 32 + (((ms * 4 + kg) ^ n) << 1);
        int2 pw;
        pw.x = pack_bf16(p0, p1);
        pw.y = pack_bf16(p2, p3);
        *reinterpret_cast<int2*>(&Pwi[qg][po]) = pw;
      }
    } else {
#pragma unroll
      for (int ms = 0; ms < 4; ++ms) {
        const int kbase = ms * 16 + kg * 4;
        float p[4];
#pragma unroll
        for (int r = 0; r < 4; ++r) {
          const float e = __expf(aS[ms][r]);
          p[r] = (kbase + r < qq) ? e : 0.0f;
          l_acc[qg] += p[r];
        }
        const int po = n * 32 + (((ms * 4 + kg) ^ n) << 1);
        int2 pw;
        pw.x = pack_bf16(p[0], p[1]);
        pw.y = pack_bf16(p[2], p[3]);
        *reinterpret_cast<int2*>(&Pwi[qg][po]) = pw;
      }
    }
  };
  // PV for both q-groups: each V fragment used twice.
  auto pv2 = [&](const bf16x8 (&vf)[2][4]) {
    __builtin_amdgcn_s_setprio(1);
#pragma unroll
    for (int ks = 0; ks < 2; ++ks) {
      const int ga = (ks * 8 + kg * 2) ^ n;
      union { ushort4 uu[2]; bf16x8 vv; } pr[2];
#pragma unroll
      for (int qg = 0; qg < 2; ++qg) {
        const __hip_bfloat16* pp = &Ps[w][qg][0] + n * 64;
        pr[qg].uu[0] = *reinterpret_cast<const ushort4*>(pp + ga * 4);
        pr[qg].uu[1] = *reinterpret_cast<const ushort4*>(pp + (ga ^ 1) * 4);
      }
#pragma unroll
      for (int mo = 0; mo < 4; ++mo) {
        accO[0][mo] = __builtin_amdgcn_mfma_f32_16x16x32_bf16(vf[ks][mo], pr[0].vv, accO[0][mo], 0, 0, 0);
        accO[1][mo] = __builtin_amdgcn_mfma_f32_16x16x32_bf16(vf[ks][mo], pr[1].vv, accO[1][mo], 0, 0, 0);
      }
    }
    __builtin_amdgcn_s_setprio(0);
  };
  // PV for qg1 only (tile 2u+1: qg0 fully masked).
  auto pv1 = [&](const bf16x8 (&vf)[2][4]) {
    __builtin_amdgcn_s_setprio(1);
#pragma unroll
    for (int ks = 0; ks < 2; ++ks) {
      const int ga = (ks * 8 + kg * 2) ^ n;
      union { ushort4 uu[2]; bf16x8 vv; } pr;
      const __hip_bfloat16* pp = &Ps[w][1][0] + n * 64;
      pr.uu[0] = *reinterpret_cast<const ushort4*>(pp + ga * 4);
      pr.uu[1] = *reinterpret_cast<const ushort4*>(pp + (ga ^ 1) * 4);
#pragma unroll
      for (int mo = 0; mo < 4; ++mo)
        accO[1][mo] = __builtin_amdgcn_mfma_f32_16x16x32_bf16(vf[ks][mo], pr.vv, accO[1][mo], 0, 0, 0);
    }
    __builtin_amdgcn_s_setprio(0);
  };

  // prologue: stage pair 0 (tiles 0,1 always exist)
  stage2(0, 0);

  int cur = 0;
  for (int p = 0; p < u; ++p) {   // full pairs: tiles 2p, 2p+1 (< 2u)
    asm volatile("" ::: "memory");
    __builtin_amdgcn_s_barrier();  // all waves done reading Ks[cur^1]
    asm volatile("" ::: "memory");

    bf16x8 vfA[2][4];
    loadV(2 * p, vfA);
    asm volatile("" ::: "memory");
    stage2(2 * p + 2, cur ^ 1);    // always valid: p+1 <= u
    // outstanding: K-pair-p(4 oldest) + vfA(8) + K-pair-p+1(4) = 16
    asm volatile("s_waitcnt vmcnt(12)" ::: "memory");
    __builtin_amdgcn_s_barrier();  // pair-p K landed for all waves
    asm volatile("" ::: "memory");

    f32x4 aS[2][4];
    // tile A = 2p
    computeS2(&Ks[cur][0], aS);
    softmaxStore(aS[0], 0, 0);
    softmaxStore(aS[1], 1, 0);
    pv2(vfA);

    // tile B = 2p+1 (sync-free)
    bf16x8 vfB[2][4];
    loadV(2 * p + 1, vfB);
    computeS2(&Ks[cur][TEL_], aS);
    softmaxStore(aS[0], 0, 0);
    softmaxStore(aS[1], 1, 0);
    pv2(vfB);

    cur ^= 1;
  }

  // epilogue pair: tiles 2u (qg0 diag, qg1 full), 2u+1 (qg1 diag only)
  {
    asm volatile("" ::: "memory");
    __builtin_amdgcn_s_barrier();
    asm volatile("" ::: "memory");
    bf16x8 vfA[2][4];
    loadV(2 * u, vfA);
    // outstanding: K-pair-u(4 oldest) + vfA(8) = 12
    asm volatile("s_waitcnt vmcnt(8)" ::: "memory");
    __builtin_amdgcn_s_barrier();
    asm volatile("" ::: "memory");

    f32x4 aS[2][4];
    computeS2(&Ks[cur][0], aS);
    softmaxStore(aS[0], 0, 1);   // qg0 diagonal
    softmaxStore(aS[1], 1, 0);   // qg1 full
    pv2(vfA);

    bf16x8 vfB[2][4];
    loadV(2 * u + 1, vfB);
    computeS2(&Ks[cur][TEL_], aS);
    softmaxStore(aS[1], 1, 1);   // qg1 diagonal; qg0 fully masked -> skip
    pv1(vfB);
  }

  // ---- deferred row reductions + epilogue ----
#pragma unroll
  for (int qg = 0; qg < 2; ++qg) {
    float la = l_acc[qg];
    la += __shfl_xor(la, 16);
    la += __shfl_xor(la, 32);
    const int query = q0 + qg * 64 + qq;
    const float inv = (query == 0) ? 0.0f : 1.0f / la;
    __hip_bfloat16* yb = y + ((size_t)b * T_ + query) * C_ + h * HS_;
#pragma unroll
    for (int mo = 0; mo < 4; ++mo) {
      int2 pkd;
      pkd.x = pack_bf16(accO[qg][mo][0] * inv, accO[qg][mo][1] * inv);
      pkd.y = pack_bf16(accO[qg][mo][2] * inv, accO[qg][mo][3] * inv);
      *reinterpret_cast<int2*>(yb + mo * 16 + kg * 4) = pkd;
    }
  }
}

// ---------------------------------------------------------------------------
extern "C" void kernel_launch(void* const* d_in, const int* in_sizes, int n_in,
                              void* d_out, int out_size, void* d_ws, size_t ws_size,
                              hipStream_t stream) {
  const float* x           = (const float*)d_in[0];
  const float* W_la        = (const float*)d_in[1];
  const float* la_coef     = (const float*)d_in[2];
  const float* kernel_beta = (const float*)d_in[3];
  const float* value_beta  = (const float*)d_in[4];
  const float* W_v         = (const float*)d_in[5];
  const float* v_coef      = (const float*)d_in[6];
  const float* W_proj      = (const float*)d_in[7];
  float* out = (float*)d_out;

  char* wsb = (char*)d_ws;
  const size_t MB = 1024u * 1024u;
  __hip_bfloat16* x16    = (__hip_bfloat16*)(wsb);            // 8 MB
  __hip_bfloat16* Wcat   = (__hip_bfloat16*)(wsb + 8 * MB);   // 4 MB (W_laT | W_vT)
  __hip_bfloat16* WprojT = (__hip_bfloat16*)(wsb + 12 * MB);  // 2 MB
  float* carr            = (float*)(wsb + 14 * MB);           // 128 KB
  float* xl              = (float*)(wsb + 16 * MB);           // 16 MB
  float* xv              = (float*)(wsb + 32 * MB);           // 16 MB
  __hip_bfloat16* kb16   = (__hip_bfloat16*)(wsb + 48 * MB);  // 8 MB
  __hip_bfloat16* vt16   = (__hip_bfloat16*)(wsb + 56 * MB);  // 8 MB
  float* loc             = (float*)(wsb + 64 * MB);           // 16 MB (own buffer)
  __hip_bfloat16* y16    = (__hip_bfloat16*)(wsb + 16 * MB);  // aliases xl (dead after prep2)
  (void)ws_size; (void)in_sizes; (void)n_in; (void)out_size;

  const int M = B_ * T_;

  prep1_kernel<<<dim3(2048 + 768), dim3(256), 0, stream>>>(x, W_la, W_v, W_proj, x16, Wcat, WprojT);
  gemm_in_kernel<<<dim3(2 * C_ / 128, M / 128), dim3(256), 0, stream>>>(x16, Wcat, xl, xv);
  prep2_kernel<<<dim3(1024 + 512), dim3(256), 0, stream>>>(xv, xl, vt16, loc, carr,
                                                           value_beta, v_coef, la_coef);
  ema_fix_norm_kernel<<<dim3(B_ * NH_ * SCN_), dim3(256), 0, stream>>>(loc, carr, kb16, la_coef, kernel_beta);
  attn_mfma_kernel<<<dim3(8 * 64), dim3(256), 0, stream>>>(kb16, vt16, y16);
  gemm_proj_kernel<<<dim3(C_ / 128, M / 64), dim3(256), 0, stream>>>(y16, WprojT, out);
}

// Round 7
// 192.102 us; speedup vs baseline: 1.1126x; 1.1126x over previous
//
#include <hip/hip_runtime.h>
#include <hip/hip_bf16.h>

#define B_  2
#define T_  2048
#define NH_ 16
#define HS_ 64
#define C_  1024
#define SCL_ 128              // EMA chunk length
#define SCN_ (T_ / SCL_)      // 16 chunks
#define NT_  (T_ / 64)        // 32 key/query tiles
#define TEL_ 4096             // elements per 64x64 tile

typedef __attribute__((ext_vector_type(8))) short bf16x8;
typedef __attribute__((ext_vector_type(4))) float f32x4;

__device__ inline int pack_bf16(float a, float b) {
  union { __hip_bfloat16 h; unsigned short u; } ua, ub;
  ua.h = __float2bfloat16(a);
  ub.h = __float2bfloat16(b);
  return (int)(((unsigned)ub.u << 16) | (unsigned)ua.u);
}

// async global->LDS 16B: global ptr is PER-LANE; LDS dest must equal
// wave-uniform base + lane*16. Callers pass per-lane g AND l = base+lane*16.
__device__ inline void gl_lds16(const __hip_bfloat16* g, __hip_bfloat16* l) {
  __builtin_amdgcn_global_load_lds(
      (const __attribute__((address_space(1))) unsigned int*)g,
      (__attribute__((address_space(3))) unsigned int*)l, 16, 0, 0);
}

// ---------------------------------------------------------------------------
// prep1: fused {fp32->bf16 x conversion} + {3x weight transpose to bf16}.
// blocks [0,2048): cvt (8 elems/thread). blocks [2048,2816): cvtT (z = id>>8).
// ---------------------------------------------------------------------------
__global__ __launch_bounds__(256) void prep1_kernel(const float* __restrict__ x,
                                                    const float* __restrict__ W_la,
                                                    const float* __restrict__ W_v,
                                                    const float* __restrict__ W_proj,
                                                    __hip_bfloat16* __restrict__ x16,
                                                    __hip_bfloat16* __restrict__ Wcat,
                                                    __hip_bfloat16* __restrict__ WprojT) {
  __shared__ __hip_bfloat16 tile[64][66];
  const int bid = (int)blockIdx.x;
  if (bid < 2048) {
    const int i = (bid * 256 + (int)threadIdx.x) * 8;
    const float4 a = *reinterpret_cast<const float4*>(x + i);
    const float4 b = *reinterpret_cast<const float4*>(x + i + 4);
    union { int s[4]; int4 v; } u;
    u.s[0] = pack_bf16(a.x, a.y);
    u.s[1] = pack_bf16(a.z, a.w);
    u.s[2] = pack_bf16(b.x, b.y);
    u.s[3] = pack_bf16(b.z, b.w);
    *reinterpret_cast<int4*>(x16 + i) = u.v;
    return;
  }
  const int id = bid - 2048;        // 0..767
  const int z = id >> 8;            // 0..2
  const int rem = id & 255;
  const int bx = rem & 15, by = rem >> 4;
  const float* W = (z == 0) ? W_la : (z == 1) ? W_v : W_proj;
  __hip_bfloat16* WT = (z == 2) ? WprojT : Wcat + (size_t)z * C_ * C_;
  const int w = threadIdx.x >> 6, l = threadIdx.x & 63;
  const int n0 = bx * 64, k0 = by * 64;
#pragma unroll
  for (int r = 0; r < 16; ++r) {
    const int k = k0 + w * 16 + r;
    tile[w * 16 + r][l] = __float2bfloat16(W[(size_t)k * C_ + n0 + l]);
  }
  __syncthreads();
#pragma unroll
  for (int r = 0; r < 16; ++r) {
    const int nn = w * 16 + r;
    WT[(size_t)(n0 + nn) * C_ + k0 + l] = tile[l][nn];
  }
}

// ---------------------------------------------------------------------------
// Combined input GEMM: [xl | xv] = x16(4096x1024) @ Wcat(2048x1024)^T.
// 2-phase double-buffered pipeline, counted vmcnt, raw s_barrier.
// ---------------------------------------------------------------------------
__global__ __launch_bounds__(256) void gemm_in_kernel(const __hip_bfloat16* __restrict__ A,
                                                      const __hip_bfloat16* __restrict__ BT,
                                                      float* __restrict__ C0,
                                                      float* __restrict__ C1) {
  __shared__ __hip_bfloat16 As[2 * 128 * 32];
  __shared__ __hip_bfloat16 Bs[2 * 128 * 32];
  const int tid = threadIdx.x;
  const int m0 = blockIdx.y * 128, n0 = blockIdx.x * 128;
  const int w = tid >> 6, l = tid & 63;
  const int n = l & 15, kg = l >> 4;
  const int m0w = (w & 1) * 64, n0w = (w >> 1) * 64;

  const int r0 = tid >> 2, o0 = (tid & 3) * 8;
  const __hip_bfloat16* ag0 = A + (size_t)(m0 + r0) * C_ + o0;
  const __hip_bfloat16* ag1 = A + (size_t)(m0 + 64 + r0) * C_ + o0;
  const __hip_bfloat16* bg0 = BT + (size_t)(n0 + r0) * C_ + o0;
  const __hip_bfloat16* bg1 = BT + (size_t)(n0 + 64 + r0) * C_ + o0;

  f32x4 acc[4][4];
#pragma unroll
  for (int i = 0; i < 4; ++i)
#pragma unroll
    for (int j = 0; j < 4; ++j) acc[i][j] = f32x4{0.f, 0.f, 0.f, 0.f};

  auto stage = [&](int kk, int buf) {
    __hip_bfloat16* a = As + buf * 4096;
    __hip_bfloat16* b = Bs + buf * 4096;
    gl_lds16(ag0 + kk, a + tid * 8);
    gl_lds16(ag1 + kk, a + 2048 + tid * 8);
    gl_lds16(bg0 + kk, b + tid * 8);
    gl_lds16(bg1 + kk, b + 2048 + tid * 8);
  };

  stage(0, 0);
  int cur = 0;
  for (int k0 = 0; k0 < C_; k0 += 32) {
    asm volatile("" ::: "memory");
    __builtin_amdgcn_s_barrier();   // buf[cur^1] readers (iter-1) done
    asm volatile("" ::: "memory");
    if (k0 + 32 < C_) {
      stage(k0 + 32, cur ^ 1);
      asm volatile("s_waitcnt vmcnt(4)" ::: "memory");  // older 4 (this tile) landed
    } else {
      asm volatile("s_waitcnt vmcnt(0)" ::: "memory");
    }
    __builtin_amdgcn_s_barrier();   // all waves' tile-k0 DMAs landed
    asm volatile("" ::: "memory");

    const __hip_bfloat16* Ab = As + cur * 4096;
    const __hip_bfloat16* Bb = Bs + cur * 4096;
    bf16x8 af[4], bf[4];
#pragma unroll
    for (int ms = 0; ms < 4; ++ms)
      af[ms] = *reinterpret_cast<const bf16x8*>(Ab + (m0w + ms * 16 + n) * 32 + kg * 8);
#pragma unroll
    for (int ns = 0; ns < 4; ++ns)
      bf[ns] = *reinterpret_cast<const bf16x8*>(Bb + (n0w + ns * 16 + n) * 32 + kg * 8);
#pragma unroll
    for (int ms = 0; ms < 4; ++ms)
#pragma unroll
      for (int ns = 0; ns < 4; ++ns)
        acc[ms][ns] = __builtin_amdgcn_mfma_f32_16x16x32_bf16(af[ms], bf[ns], acc[ms][ns], 0, 0, 0);
    cur ^= 1;
  }

  float* Cb = (n0 < C_) ? C0 : C1;
  const int nc = (n0 < C_) ? n0 : n0 - C_;
#pragma unroll
  for (int ms = 0; ms < 4; ++ms) {
#pragma unroll
    for (int r = 0; r < 4; ++r) {
      const int row = m0 + m0w + ms * 16 + kg * 4 + r;
      float* cp = Cb + (size_t)row * C_ + nc + n0w + n;
#pragma unroll
      for (int ns = 0; ns < 4; ++ns) cp[ns * 16] = acc[ms][ns][r];
    }
  }
}

// ---------------------------------------------------------------------------
// Projection GEMM: out = y16(4096x1024) @ WprojT(1024x1024)^T, fp32 out.
// ---------------------------------------------------------------------------
__global__ __launch_bounds__(256) void gemm_proj_kernel(const __hip_bfloat16* __restrict__ A,
                                                        const __hip_bfloat16* __restrict__ BT,
                                                        float* __restrict__ Cout) {
  __shared__ __hip_bfloat16 As[2 * 64 * 32];
  __shared__ __hip_bfloat16 Bs[2 * 128 * 32];
  const int tid = threadIdx.x;
  const int m0 = blockIdx.y * 64, n0 = blockIdx.x * 128;
  const int w = tid >> 6, l = tid & 63;
  const int n = l & 15, kg = l >> 4;

  const int r0 = tid >> 2, o0 = (tid & 3) * 8;
  const __hip_bfloat16* ag = A + (size_t)(m0 + r0) * C_ + o0;
  const __hip_bfloat16* bg0 = BT + (size_t)(n0 + r0) * C_ + o0;
  const __hip_bfloat16* bg1 = BT + (size_t)(n0 + 64 + r0) * C_ + o0;

  f32x4 acc[4][2];
#pragma unroll
  for (int i = 0; i < 4; ++i)
#pragma unroll
    for (int j = 0; j < 2; ++j) acc[i][j] = f32x4{0.f, 0.f, 0.f, 0.f};

  auto stage = [&](int kk, int buf) {
    __hip_bfloat16* a = As + buf * 2048;
    __hip_bfloat16* b = Bs + buf * 4096;
    gl_lds16(ag + kk, a + tid * 8);
    gl_lds16(bg0 + kk, b + tid * 8);
    gl_lds16(bg1 + kk, b + 2048 + tid * 8);
  };

  stage(0, 0);
  int cur = 0;
  for (int k0 = 0; k0 < C_; k0 += 32) {
    asm volatile("" ::: "memory");
    __builtin_amdgcn_s_barrier();
    asm volatile("" ::: "memory");
    if (k0 + 32 < C_) {
      stage(k0 + 32, cur ^ 1);
      asm volatile("s_waitcnt vmcnt(3)" ::: "memory");
    } else {
      asm volatile("s_waitcnt vmcnt(0)" ::: "memory");
    }
    __builtin_amdgcn_s_barrier();
    asm volatile("" ::: "memory");

    const __hip_bfloat16* Ab = As + cur * 2048;
    const __hip_bfloat16* Bb = Bs + cur * 4096;
    bf16x8 af[4], bf[2];
#pragma unroll
    for (int ms = 0; ms < 4; ++ms)
      af[ms] = *reinterpret_cast<const bf16x8*>(Ab + (ms * 16 + n) * 32 + kg * 8);
#pragma unroll
    for (int ns = 0; ns < 2; ++ns)
      bf[ns] = *reinterpret_cast<const bf16x8*>(Bb + (w * 32 + ns * 16 + n) * 32 + kg * 8);
#pragma unroll
    for (int ms = 0; ms < 4; ++ms)
#pragma unroll
      for (int ns = 0; ns < 2; ++ns)
        acc[ms][ns] = __builtin_amdgcn_mfma_f32_16x16x32_bf16(af[ms], bf[ns], acc[ms][ns], 0, 0, 0);
    cur ^= 1;
  }

#pragma unroll
  for (int ms = 0; ms < 4; ++ms) {
#pragma unroll
    for (int r = 0; r < 4; ++r) {
      const int row = m0 + ms * 16 + kg * 4 + r;
      float* cp = Cout + (size_t)row * C_ + n0 + w * 32 + n;
#pragma unroll
      for (int ns = 0; ns < 2; ++ns) cp[ns * 16] = acc[ms][ns][r];
    }
  }
}

// ---------------------------------------------------------------------------
// prep2: fused {vprep} (blocks [0,1024)) + {EMA full: warmup-carry + scan +
// normalize + kb16 emit} (blocks [1024,1536)).
// Carry truncation: alpha <= 0.9 -> alpha^128 <= 1.4e-6, far below bf16
// output resolution, so each chunk's starting state is recovered by scanning
// ONLY the previous chunk (zero-init warmup). This kills ema_fix_norm, the
// loc buffer (32 MB HBM round-trip) and carr entirely.
// ---------------------------------------------------------------------------
__global__ __launch_bounds__(256) void prep2_kernel(const float* __restrict__ xv,
                                                    const float* __restrict__ xl,
                                                    __hip_bfloat16* __restrict__ vt,
                                                    __hip_bfloat16* __restrict__ kb16,
                                                    const float* __restrict__ value_beta,
                                                    const float* __restrict__ v_coef,
                                                    const float* __restrict__ la_coef,
                                                    const float* __restrict__ kernel_beta) {
  __shared__ float4 smem4[2048];  // 32 KB, shared by both paths
  const int bid = (int)blockIdx.x;
  if (bid < 1024) {
    // ---- vprep ----
    __hip_bfloat16 (*tile)[66] = reinterpret_cast<__hip_bfloat16(*)[66]>(smem4);
    const int tc = bid % NT_;
    const int bh = bid / NT_;
    const int h = bh % NH_, b = bh / NH_;
    const int t0 = tc * 64;
    const int w = threadIdx.x >> 6, l = threadIdx.x & 63;

    const float c = v_coef[h];
    const float vb = expf(value_beta[h] * 10.0f);

    for (int r = 0; r < 16; ++r) {
      const int tl = w * 16 + r;
      const int t = t0 + tl;
      const float* base = xv + ((size_t)b * T_ + t) * C_ + h * HS_ + l;
      const float cu = base[0];
      const float nxt = (t + 1 < T_) ? base[C_] : 0.0f;
      float val = nxt * (1.0f - c) + cu * c;
      float ssum = val * val;
#pragma unroll
      for (int m = 32; m; m >>= 1) ssum += __shfl_xor(ssum, m);
      tile[tl][l] = __float2bfloat16(val * (vb / sqrtf(ssum)));
    }
    __syncthreads();
    __hip_bfloat16* vtb = vt + (size_t)(bh * NT_ + tc) * TEL_;
    const int kk = l >> 3, j = l & 7;  // l = key
    for (int rr = 0; rr < 16; ++rr) {
      const int hs = w * 16 + rr;
      vtb[(kk * 64 + hs) * 8 + j] = tile[l][hs];
    }
    return;
  }
  // ---- EMA: warmup(prev chunk) -> scan(own chunk) -> norm -> kb16 slots ----
  {
    float* buf = reinterpret_cast<float*>(smem4);  // 128 x 64 fp32 = 32 KB
    const int idx = bid - 1024;
    const int c = idx % SCN_;
    const int bh = idx / SCN_;
    const int b = bh / NH_, h = bh % NH_;
    const int tid = threadIdx.x;

    const float alpha = la_coef[h];
    const float onema = 1.0f - alpha;
    const float kbs = expf(fminf(kernel_beta[h] * 10.0f, 5.0f));
    const float4* src4 = reinterpret_cast<const float4*>(xl + (size_t)b * T_ * C_ + h * HS_);
    float4* buf4 = reinterpret_cast<float4*>(buf);

    float A = 0.0f;  // per-lane carry (lane = dim) on wave 0
    if (c > 0) {
      const int t0p = (c - 1) * SCL_;
#pragma unroll
      for (int i = 0; i < 8; ++i) {
        const int ix = tid + i * 256;
        const int tt = ix >> 4, d4 = ix & 15;
        buf4[tt * 16 + d4] = src4[(size_t)(t0p + tt) * (C_ / 4) + d4];
      }
      __syncthreads();
      if (tid < 64) {
        const int d = tid;
#pragma unroll 8
        for (int tt = 0; tt < SCL_; ++tt)
          A = alpha * A + onema * buf[tt * HS_ + d];
      }
      __syncthreads();  // warmup reads complete before restage
    }
    const int t0 = c * SCL_;
#pragma unroll
    for (int i = 0; i < 8; ++i) {
      const int ix = tid + i * 256;
      const int tt = ix >> 4, d4 = ix & 15;
      buf4[tt * 16 + d4] = src4[(size_t)(t0 + tt) * (C_ / 4) + d4];
    }
    __syncthreads();
    if (tid < 64) {
      const int d = tid;
#pragma unroll 8
      for (int tt = 0; tt < SCL_; ++tt) {
        A = alpha * A + onema * buf[tt * HS_ + d];
        buf[tt * HS_ + d] = A;
      }
    }
    __syncthreads();
    // normalize + kb-scale + slot emit (wave w: rows w*32..w*32+31)
    const int w = tid >> 6, l = tid & 63;
    __hip_bfloat16* kt = kb16 + (size_t)bh * NT_ * TEL_;
    const int g = l >> 3, j = l & 7;
    for (int rr = 0; rr < 32; ++rr) {
      const int tl = w * 32 + rr;
      const int t = t0 + tl;
      const float val = buf[tl * HS_ + l];
      float ss = val * val;
#pragma unroll
      for (int m = 32; m; m >>= 1) ss += __shfl_xor(ss, m);
      const int tile = t >> 6, key = t & 63;
      kt[(size_t)tile * TEL_ + (g * 64 + key) * 8 + j] = __float2bfloat16(val * (kbs / sqrtf(ss)));
    }
  }
}

// ---------------------------------------------------------------------------
// MFMA flash attention, V-DIRECT + 2-TILE PAIRED iterations (R5 config:
// best measured). Ks = 2 buf x 2 tiles (32 KB) + Ps 8 KB = 40960 B ->
// 4 blocks/CU. Per pair: 2 barriers serve TWO 64-key tiles; tile B sync-free.
// vmcnt: outstanding at wait = oldK(4) + vfA(8) + newK(c) -> vmcnt(8+c).
// ---------------------------------------------------------------------------
__global__ __launch_bounds__(256, 4) void attn_mfma_kernel(
    const __hip_bfloat16* __restrict__ kb,   // (BH, NT, g, key, 8) slot tiles
    const __hip_bfloat16* __restrict__ vt,   // (BH, NT, kk, hs, 8) slot tiles
    __hip_bfloat16* __restrict__ y) {        // (B, T, C) bf16
  __shared__ __hip_bfloat16 Ks[2][2 * TEL_]; // 32 KB: [buf][tile0|tile1]
  __shared__ __hip_bfloat16 Ps[4][16 * 64];  // 8 KB, XOR-swizzled granules

  const int id = (int)blockIdx.x;
  const int xcd = id & 7;
  const int s = id >> 3;                 // 0..127
  const int bh = xcd + 8 * (s & 3);      // 32 bh, grouped 4 per XCD
  const int v = s >> 2;                  // 0..31
  const int qt = (v < 16) ? (31 - v) : (v - 16);  // balanced bijection
  const int b = bh / NH_, h = bh % NH_;
  const int q0 = qt * 64;
  const int w = threadIdx.x >> 6;
  const int l = threadIdx.x & 63;
  const int n = l & 15;
  const int kg = l >> 4;
  const int qq = w * 16 + n;             // within-tile query index
  const int query = q0 + qq;
  const int lo = l * 8;                  // per-lane 16B offset (elements)
  const int tb = bh * NT_;
  const int so = w * 1024 + lo;          // per-wave stage offset (elements)

  // Q B-fragments from global slot tile (once)
  bf16x8 qf0, qf1;
  {
    const __hip_bfloat16* qtile = kb + (size_t)(tb + qt) * TEL_;
    qf0 = *reinterpret_cast<const bf16x8*>(qtile + (kg * 64 + qq) * 8);
    qf1 = *reinterpret_cast<const bf16x8*>(qtile + ((kg + 4) * 64 + qq) * 8);
  }
  // per-lane V fragment base: fragment (ks,mo) at vbase + ks*2048 + mo*128
  const __hip_bfloat16* vbase = vt + (size_t)tb * TEL_ + (kg * 64 + n) * 8;

  f32x4 accO[4];
#pragma unroll
  for (int i = 0; i < 4; ++i) accO[i] = f32x4{0.f, 0.f, 0.f, 0.f};
  float l_acc = 0.0f;

  __hip_bfloat16* Pw = Ps[w];
  int* Pwi = reinterpret_cast<int*>(Pw);

  auto stage2 = [&](int j0, int buf) {   // 4 DMAs: tiles j0, j0+1
    const size_t tg = (size_t)(tb + j0) * TEL_;
    __hip_bfloat16* Kb = &Ks[buf][0];
    gl_lds16(kb + tg + so, Kb + so);
    gl_lds16(kb + tg + so + 512, Kb + so + 512);
    gl_lds16(kb + tg + TEL_ + so, Kb + TEL_ + so);
    gl_lds16(kb + tg + TEL_ + so + 512, Kb + TEL_ + so + 512);
  };
  auto stage1 = [&](int j0, int buf) {   // 2 DMAs: tile j0 into half 0
    const size_t tg = (size_t)(tb + j0) * TEL_;
    __hip_bfloat16* Kb = &Ks[buf][0];
    gl_lds16(kb + tg + so, Kb + so);
    gl_lds16(kb + tg + so + 512, Kb + so + 512);
  };
  auto loadV = [&](int jt, bf16x8 (&vf)[2][4]) {
    const __hip_bfloat16* vp = vbase + (size_t)jt * TEL_;
#pragma unroll
    for (int ks = 0; ks < 2; ++ks)
#pragma unroll
      for (int mo = 0; mo < 4; ++mo)
        vf[ks][mo] = *reinterpret_cast<const bf16x8*>(vp + ks * 2048 + mo * 128);
  };
  auto computeS = [&](const __hip_bfloat16* Kc, f32x4 (&accS)[4]) {
    __builtin_amdgcn_s_setprio(1);
#pragma unroll
    for (int ms = 0; ms < 4; ++ms) {
      bf16x8 a0 = *reinterpret_cast<const bf16x8*>(Kc + (kg * 64 + ms * 16 + n) * 8);
      bf16x8 a1 = *reinterpret_cast<const bf16x8*>(Kc + ((kg + 4) * 64 + ms * 16 + n) * 8);
      f32x4 z{0.f, 0.f, 0.f, 0.f};
      z = __builtin_amdgcn_mfma_f32_16x16x32_bf16(a0, qf0, z, 0, 0, 0);
      accS[ms] = __builtin_amdgcn_mfma_f32_16x16x32_bf16(a1, qf1, z, 0, 0, 0);
    }
    __builtin_amdgcn_s_setprio(0);
  };
  auto softmaxStore = [&](const f32x4 (&accS)[4], bool diag) {
    if (!diag) {
#pragma unroll
      for (int ms = 0; ms < 4; ++ms) {
        const float p0 = __expf(accS[ms][0]), p1 = __expf(accS[ms][1]);
        const float p2 = __expf(accS[ms][2]), p3 = __expf(accS[ms][3]);
        l_acc += p0 + p1 + p2 + p3;
        const int po = n * 32 + (((ms * 4 + kg) ^ n) << 1);
        int2 pw;
        pw.x = pack_bf16(p0, p1);
        pw.y = pack_bf16(p2, p3);
        *reinterpret_cast<int2*>(&Pwi[po]) = pw;
      }
    } else {
#pragma unroll
      for (int ms = 0; ms < 4; ++ms) {
        const int kbase = ms * 16 + kg * 4;
        float p[4];
#pragma unroll
        for (int r = 0; r < 4; ++r) {
          const float e = __expf(accS[ms][r]);
          p[r] = (kbase + r < qq) ? e : 0.0f;
          l_acc += p[r];
        }
        const int po = n * 32 + (((ms * 4 + kg) ^ n) << 1);
        int2 pw;
        pw.x = pack_bf16(p[0], p[1]);
        pw.y = pack_bf16(p[2], p[3]);
        *reinterpret_cast<int2*>(&Pwi[po]) = pw;
      }
    }
  };
  auto pv = [&](const bf16x8 (&vf)[2][4]) {
    __builtin_amdgcn_s_setprio(1);
#pragma unroll
    for (int ks = 0; ks < 2; ++ks) {
      union { ushort4 u[2]; bf16x8 vv; } pr;
      const int ga = (ks * 8 + kg * 2) ^ n;      // granule of keys kg*8+0..3
      const __hip_bfloat16* pp = Pw + n * 64;
      pr.u[0] = *reinterpret_cast<const ushort4*>(pp + ga * 4);
      pr.u[1] = *reinterpret_cast<const ushort4*>(pp + (ga ^ 1) * 4);
#pragma unroll
      for (int mo = 0; mo < 4; ++mo)
        accO[mo] = __builtin_amdgcn_mfma_f32_16x16x32_bf16(vf[ks][mo], pr.vv, accO[mo], 0, 0, 0);
    }
    __builtin_amdgcn_s_setprio(0);
  };

  // prologue: stage first pair (or single) into buf 0
  if (qt >= 1) stage2(0, 0); else stage1(0, 0);

  int cur = 0;
  int jp = 0;
  for (; jp + 1 <= qt; jp += 2) {
    // barrier #1: all waves done reading Ks[cur^1]
    asm volatile("" ::: "memory");
    __builtin_amdgcn_s_barrier();
    asm volatile("" ::: "memory");

    bf16x8 vfA[2][4];
    loadV(jp, vfA);                     // 8 V loads (oldest after oldK)
    asm volatile("" ::: "memory");      // pin V issue before K-DMA

    const int nx = jp + 2;
    if (nx + 1 <= qt) {
      stage2(nx, cur ^ 1);
      asm volatile("s_waitcnt vmcnt(12)" ::: "memory");  // drain oldK(4)
    } else if (nx <= qt) {
      stage1(nx, cur ^ 1);
      asm volatile("s_waitcnt vmcnt(10)" ::: "memory");
    } else {
      asm volatile("s_waitcnt vmcnt(8)" ::: "memory");
    }
    // barrier #2: every wave's pair-K DMAs have landed
    __builtin_amdgcn_s_barrier();
    asm volatile("" ::: "memory");

    // ---- tile A (index jp, never diagonal in pair loop) ----
    f32x4 accS[4];
    computeS(&Ks[cur][0], accS);
    softmaxStore(accS, false);
    pv(vfA);

    asm volatile("" ::: "memory");  // tile A P-reads before tile B P-writes

    // ---- tile B (index jp+1, diag iff == qt); sync-free ----
    bf16x8 vfB[2][4];
    loadV(jp + 1, vfB);             // hidden under S(B)+softmax(B)
    computeS(&Ks[cur][TEL_], accS);
    softmaxStore(accS, jp + 1 == qt);
    pv(vfB);

    cur ^= 1;
  }
  if (jp <= qt) {  // peeled single (diagonal) tile
    asm volatile("" ::: "memory");
    __builtin_amdgcn_s_barrier();
    asm volatile("" ::: "memory");
    bf16x8 vfA[2][4];
    loadV(jp, vfA);
    asm volatile("s_waitcnt vmcnt(8)" ::: "memory");  // drain the 2 oldK
    __builtin_amdgcn_s_barrier();
    asm volatile("" ::: "memory");
    f32x4 accS[4];
    computeS(&Ks[cur][0], accS);
    softmaxStore(accS, true);
    pv(vfA);
  }

  // ---- deferred row reduction + epilogue ----
  l_acc += __shfl_xor(l_acc, 16);
  l_acc += __shfl_xor(l_acc, 32);
  const float inv = (query == 0) ? 0.0f : 1.0f / l_acc;
  __hip_bfloat16* yb = y + ((size_t)b * T_ + query) * C_ + h * HS_;
#pragma unroll
  for (int mo = 0; mo < 4; ++mo) {
    int2 pkd;
    pkd.x = pack_bf16(accO[mo][0] * inv, accO[mo][1] * inv);
    pkd.y = pack_bf16(accO[mo][2] * inv, accO[mo][3] * inv);
    *reinterpret_cast<int2*>(yb + mo * 16 + kg * 4) = pkd;
  }
}

// ---------------------------------------------------------------------------
extern "C" void kernel_launch(void* const* d_in, const int* in_sizes, int n_in,
                              void* d_out, int out_size, void* d_ws, size_t ws_size,
                              hipStream_t stream) {
  const float* x           = (const float*)d_in[0];
  const float* W_la        = (const float*)d_in[1];
  const float* la_coef     = (const float*)d_in[2];
  const float* kernel_beta = (const float*)d_in[3];
  const float* value_beta  = (const float*)d_in[4];
  const float* W_v         = (const float*)d_in[5];
  const float* v_coef      = (const float*)d_in[6];
  const float* W_proj      = (const float*)d_in[7];
  float* out = (float*)d_out;

  char* wsb = (char*)d_ws;
  const size_t MB = 1024u * 1024u;
  __hip_bfloat16* x16    = (__hip_bfloat16*)(wsb);            // 8 MB
  __hip_bfloat16* Wcat   = (__hip_bfloat16*)(wsb + 8 * MB);   // 4 MB (W_laT | W_vT)
  __hip_bfloat16* WprojT = (__hip_bfloat16*)(wsb + 12 * MB);  // 2 MB
  float* xl              = (float*)(wsb + 16 * MB);           // 16 MB
  float* xv              = (float*)(wsb + 32 * MB);           // 16 MB
  __hip_bfloat16* kb16   = (__hip_bfloat16*)(wsb + 48 * MB);  // 8 MB
  __hip_bfloat16* vt16   = (__hip_bfloat16*)(wsb + 56 * MB);  // 8 MB
  __hip_bfloat16* y16    = (__hip_bfloat16*)(wsb + 64 * MB);  // 8 MB (xl still
                                                              //  live during prep2)
  (void)ws_size; (void)in_sizes; (void)n_in; (void)out_size;

  const int M = B_ * T_;

  prep1_kernel<<<dim3(2048 + 768), dim3(256), 0, stream>>>(x, W_la, W_v, W_proj, x16, Wcat, WprojT);
  gemm_in_kernel<<<dim3(2 * C_ / 128, M / 128), dim3(256), 0, stream>>>(x16, Wcat, xl, xv);
  prep2_kernel<<<dim3(1024 + 512), dim3(256), 0, stream>>>(xv, xl, vt16, kb16,
                                                           value_beta, v_coef, la_coef, kernel_beta);
  attn_mfma_kernel<<<dim3(8 * 128), dim3(256), 0, stream>>>(kb16, vt16, y16);
  gemm_proj_kernel<<<dim3(C_ / 128, M / 64), dim3(256), 0, stream>>>(y16, WprojT, out);
}